// Round 3
// baseline (2092.118 us; speedup 1.0000x reference)
//
#include <hip/hip_runtime.h>

// Dims: x[b=32][i=2048][n=16], W[j=64][i=2048][m=32][n=16], bias[j][m], out v[b][j][m]
constexpr int B = 32, I = 2048, J = 64, M = 32, N = 16;
constexpr float FEPS = 1e-8f;
constexpr int SLICE_FLOATS = B * J * M;   // 65536 floats = 256 KB per partial slice

// Heavy pass: grid = 2n blocks (bh = bid&1, icg = bid>>1), 512 threads = 8 waves.
// lane = j (wave-local softmax over the 64 parent capsules), wave wv owns b = bh*16 + wv*2 + {0,1}.
// Each W-row ds_read feeds FMAs for BOTH b's (halves LDS-read duplication vs 16-wave/1-b shape).
// MODE 0: c = 1/64 exactly (softmax of zero logits). MODE 1: logit = veff . u_hat.
// STORE: unique slice per icg -> plain float4 stores. !STORE: atomicAdd into slice (icg % nslice).
template<int MODE, bool STORE>
__global__ __launch_bounds__(512)
void route_pass(const float* __restrict__ W, const float* __restrict__ x,
                const float* __restrict__ veff, float* __restrict__ P,
                int ICdyn, int nslice)
{
    __shared__ float4 Wl[8192];                 // 128 KB: W[:, i, :, :] (XOR-swizzled)
    const int tid = threadIdx.x;
    const int j   = tid & 63;
    const int wv  = tid >> 6;                   // 0..7
    const int bh  = blockIdx.x & 1;
    const int icg = blockIdx.x >> 1;
    const int b0  = bh * 16 + wv * 2;
    const int swz  = (j & 7) << 4;
    const int rowb = j << 11;                   // j * 2048 bytes

    float acc0[M], acc1[M];
    #pragma unroll
    for (int m = 0; m < M; ++m) { acc0[m] = 0.f; acc1[m] = 0.f; }

    for (int ii = 0; ii < ICdyn; ++ii) {
        const int i = icg * ICdyn + ii;
        __syncthreads();                        // previous iter's LDS reads done
        // ---- stage W[:, i, :, :]: 8192 float4, 16 per thread, coalesced ----
        #pragma unroll
        for (int k = 0; k < 16; ++k) {
            const int f   = k * 512 + tid;      // float4 index: f = jp*128 + rem
            const int jp  = f >> 7;
            const int rem = f & 127;
            const float4 w4 = *(const float4*)(W + (((size_t)jp << 20) + (size_t)i * 512 + (rem << 2)));
            *(float4*)((char*)Wl + ((f * 16) ^ ((jp & 7) << 4))) = w4;
        }
        // x rows for the wave's two b's (wave-uniform addresses -> broadcast)
        const float* xr0 = x + (((size_t)b0 << 15) + (i << 4));
        const float* xr1 = xr0 + 32768;
        const float4 xa0 = *(const float4*)(xr0 + 0), xa1 = *(const float4*)(xr0 + 4);
        const float4 xa2 = *(const float4*)(xr0 + 8), xa3 = *(const float4*)(xr0 + 12);
        const float4 xb0 = *(const float4*)(xr1 + 0), xb1 = *(const float4*)(xr1 + 4);
        const float4 xb2 = *(const float4*)(xr1 + 8), xb3 = *(const float4*)(xr1 + 12);
        __syncthreads();

        // ---- u_hat[m] for both b; logit (MODE 1) ----
        float uh0[M], uh1[M];
        float logit0 = 0.f, logit1 = 0.f;
        const char* wb = (const char*)Wl;
        #pragma unroll
        for (int mq = 0; mq < 8; ++mq) {
            float4 vv0 = make_float4(0.f,0.f,0.f,0.f), vv1 = vv0;
            if (MODE != 0) {
                vv0 = *(const float4*)(veff + ((((size_t)b0 << 6) | j) << 5) + (mq << 2));
                vv1 = *(const float4*)(veff + ((((size_t)(b0+1) << 6) | j) << 5) + (mq << 2));
            }
            #pragma unroll
            for (int mi = 0; mi < 4; ++mi) {
                const int m  = mq * 4 + mi;
                const int rb = rowb + (m << 6);
                const float4 w0 = *(const float4*)(wb + ((rb +  0) ^ swz));
                const float4 w1 = *(const float4*)(wb + ((rb + 16) ^ swz));
                const float4 w2 = *(const float4*)(wb + ((rb + 32) ^ swz));
                const float4 w3 = *(const float4*)(wb + ((rb + 48) ^ swz));
                float u0 = w0.x * xa0.x, u1 = w0.x * xb0.x;
                u0 = fmaf(w0.y, xa0.y, u0); u1 = fmaf(w0.y, xb0.y, u1);
                u0 = fmaf(w0.z, xa0.z, u0); u1 = fmaf(w0.z, xb0.z, u1);
                u0 = fmaf(w0.w, xa0.w, u0); u1 = fmaf(w0.w, xb0.w, u1);
                u0 = fmaf(w1.x, xa1.x, u0); u1 = fmaf(w1.x, xb1.x, u1);
                u0 = fmaf(w1.y, xa1.y, u0); u1 = fmaf(w1.y, xb1.y, u1);
                u0 = fmaf(w1.z, xa1.z, u0); u1 = fmaf(w1.z, xb1.z, u1);
                u0 = fmaf(w1.w, xa1.w, u0); u1 = fmaf(w1.w, xb1.w, u1);
                u0 = fmaf(w2.x, xa2.x, u0); u1 = fmaf(w2.x, xb2.x, u1);
                u0 = fmaf(w2.y, xa2.y, u0); u1 = fmaf(w2.y, xb2.y, u1);
                u0 = fmaf(w2.z, xa2.z, u0); u1 = fmaf(w2.z, xb2.z, u1);
                u0 = fmaf(w2.w, xa2.w, u0); u1 = fmaf(w2.w, xb2.w, u1);
                u0 = fmaf(w3.x, xa3.x, u0); u1 = fmaf(w3.x, xb3.x, u1);
                u0 = fmaf(w3.y, xa3.y, u0); u1 = fmaf(w3.y, xb3.y, u1);
                u0 = fmaf(w3.z, xa3.z, u0); u1 = fmaf(w3.z, xb3.z, u1);
                u0 = fmaf(w3.w, xa3.w, u0); u1 = fmaf(w3.w, xb3.w, u1);
                uh0[m] = u0; uh1[m] = u1;
                if (MODE != 0) {
                    const float vm0 = (mi == 0) ? vv0.x : (mi == 1) ? vv0.y : (mi == 2) ? vv0.z : vv0.w;
                    const float vm1 = (mi == 0) ? vv1.x : (mi == 1) ? vv1.y : (mi == 2) ? vv1.z : vv1.w;
                    logit0 = fmaf(u0, vm0, logit0);
                    logit1 = fmaf(u1, vm1, logit1);
                }
            }
        }
        // ---- softmax over j (wave-local: 64 lanes = 64 j), two b's at once ----
        float c0, c1;
        if (MODE == 0) {
            c0 = 1.0f / 64.0f; c1 = c0;
        } else {
            float mx0 = logit0, mx1 = logit1;
            #pragma unroll
            for (int off = 32; off >= 1; off >>= 1) {
                mx0 = fmaxf(mx0, __shfl_xor(mx0, off, 64));
                mx1 = fmaxf(mx1, __shfl_xor(mx1, off, 64));
            }
            const float e0 = __expf(logit0 - mx0);
            const float e1 = __expf(logit1 - mx1);
            float s0 = e0, s1 = e1;
            #pragma unroll
            for (int off = 32; off >= 1; off >>= 1) {
                s0 += __shfl_xor(s0, off, 64);
                s1 += __shfl_xor(s1, off, 64);
            }
            c0 = e0 / s0; c1 = e1 / s1;
        }
        #pragma unroll
        for (int m = 0; m < M; ++m) {
            acc0[m] = fmaf(c0, uh0[m], acc0[m]);
            acc1[m] = fmaf(c1, uh1[m], acc1[m]);
        }
    }

    // ---- write partials: P[slice][b][j][m] ----
    if (STORE) {
        float* pp0 = P + ((size_t)icg * SLICE_FLOATS) + ((((size_t)b0 << 6) | j) << 5);
        float* pp1 = pp0 + (64 << 5);
        #pragma unroll
        for (int mq = 0; mq < 8; ++mq) {
            *(float4*)(pp0 + (mq << 2)) = make_float4(acc0[mq*4], acc0[mq*4+1], acc0[mq*4+2], acc0[mq*4+3]);
            *(float4*)(pp1 + (mq << 2)) = make_float4(acc1[mq*4], acc1[mq*4+1], acc1[mq*4+2], acc1[mq*4+3]);
        }
    } else {
        const int slice = icg % nslice;
        float* pp0 = P + ((size_t)slice * SLICE_FLOATS) + ((((size_t)b0 << 6) | j) << 5);
        float* pp1 = pp0 + (64 << 5);
        #pragma unroll
        for (int m = 0; m < M; ++m) { atomicAdd(pp0 + m, acc0[m]); atomicAdd(pp1 + m, acc1[m]); }
    }
}

// Reduce nsum slices, add bias, squash. 256 thr = 8 groups of 32 lanes (lane = m).
// If vold != null: vout[idx] = vold[idx] + v (running sum for logits-linearity). vold may alias vout.
__global__ __launch_bounds__(256)
void reduce_squash(const float* __restrict__ P, const float* __restrict__ bias,
                   float* __restrict__ vout, const float* __restrict__ vold, int nsum)
{
    const int tid = threadIdx.x;
    const int m = tid & 31;
    const int g = tid >> 5;
    const int pair = blockIdx.x * 8 + g;        // 0..2047 = b*64 + j
    const int j = pair & 63;
    const float* base = P + (((size_t)pair) << 5) + m;
    float s0 = 0.f, s1 = 0.f, s2 = 0.f, s3 = 0.f;
    int q = 0;
    for (; q + 4 <= nsum; q += 4) {
        s0 += base[(size_t)(q + 0) * SLICE_FLOATS];
        s1 += base[(size_t)(q + 1) * SLICE_FLOATS];
        s2 += base[(size_t)(q + 2) * SLICE_FLOATS];
        s3 += base[(size_t)(q + 3) * SLICE_FLOATS];
    }
    for (; q < nsum; ++q) s0 += base[(size_t)q * SLICE_FLOATS];
    float s = (s0 + s1) + (s2 + s3);
    s += bias[(j << 5) + m];
    float n2 = s * s;
    n2 += __shfl_xor(n2, 16, 64);
    n2 += __shfl_xor(n2,  8, 64);
    n2 += __shfl_xor(n2,  4, 64);
    n2 += __shfl_xor(n2,  2, 64);
    n2 += __shfl_xor(n2,  1, 64);
    float v = s * (n2 / (1.f + n2)) / sqrtf(n2 + FEPS);
    if (vold) v += vold[(((size_t)pair) << 5) + m];
    vout[(((size_t)pair) << 5) + m] = v;
}

extern "C" void kernel_launch(void* const* d_in, const int* in_sizes, int n_in,
                              void* d_out, int out_size, void* d_ws, size_t ws_size,
                              hipStream_t stream)
{
    const float* x    = (const float*)d_in[0];
    const float* W    = (const float*)d_in[1];
    const float* bias = (const float*)d_in[2];
    float* out = (float*)d_out;

    float* P = (float*)d_ws;
    float* vrun = out;                          // running v lives in d_out

    const size_t wsFloats = ws_size / sizeof(float);
    const int cap = (int)(wsFloats / SLICE_FLOATS);     // slices that fit in ws
    int n = 1;
    while (n * 2 <= cap && n * 2 <= 128) n *= 2;        // largest pow2 <= min(cap,128)
    const bool store = (n >= 32);                       // need >= 8 MB ws for store path

    if (store) {
        const int IC = I / n;                           // i's per block
        const dim3 grid(2 * n);
        route_pass<0, true><<<grid, 512, 0, stream>>>(W, x, nullptr, P, IC, n);
        reduce_squash<<<256, 256, 0, stream>>>(P, bias, vrun, nullptr, n);      // vrun = v0
        route_pass<1, true><<<grid, 512, 0, stream>>>(W, x, vrun, P, IC, n);
        reduce_squash<<<256, 256, 0, stream>>>(P, bias, vrun, vrun, n);         // vrun = v0 + v1
        route_pass<1, true><<<grid, 512, 0, stream>>>(W, x, vrun, P, IC, n);
        reduce_squash<<<256, 256, 0, stream>>>(P, bias, out, nullptr, n);       // final v
    } else {
        const int nslice = (n < 1) ? 1 : n;
        const size_t pBytes = (size_t)nslice * SLICE_FLOATS * sizeof(float);
        hipMemsetAsync(P, 0, pBytes, stream);
        route_pass<0, false><<<256, 512, 0, stream>>>(W, x, nullptr, P, 16, nslice);
        reduce_squash<<<256, 256, 0, stream>>>(P, bias, vrun, nullptr, nslice);
        hipMemsetAsync(P, 0, pBytes, stream);
        route_pass<1, false><<<256, 512, 0, stream>>>(W, x, vrun, P, 16, nslice);
        reduce_squash<<<256, 256, 0, stream>>>(P, bias, vrun, vrun, nslice);
        hipMemsetAsync(P, 0, pBytes, stream);
        route_pass<1, false><<<256, 512, 0, stream>>>(W, x, vrun, P, 16, nslice);
        reduce_squash<<<256, 256, 0, stream>>>(P, bias, out, nullptr, nslice);
    }
}

// Round 4
// 1838.640 us; speedup vs baseline: 1.1379x; 1.1379x over previous
//
#include <hip/hip_runtime.h>

// Dims: x[b=32][i=2048][n=16], W[j=64][i=2048][m=32][n=16], bias[j=64][m=32], out v[b=32][j=64][m=32]
// ws: Z[b=32][i=2048] (256 KB) — softmax denominators. (ws >= 256 KB established r1-r3.)
constexpr float FEPS = 1e-8f;

__device__ __forceinline__ float dot16(const float4 w0, const float4 w1,
                                       const float4 w2, const float4 w3,
                                       const float4 x0, const float4 x1,
                                       const float4 x2, const float4 x3)
{
    float u = w0.x * x0.x;
    u = fmaf(w0.y, x0.y, u); u = fmaf(w0.z, x0.z, u); u = fmaf(w0.w, x0.w, u);
    u = fmaf(w1.x, x1.x, u); u = fmaf(w1.y, x1.y, u); u = fmaf(w1.z, x1.z, u); u = fmaf(w1.w, x1.w, u);
    u = fmaf(w2.x, x2.x, u); u = fmaf(w2.y, x2.y, u); u = fmaf(w2.z, x2.z, u); u = fmaf(w2.w, x2.w, u);
    u = fmaf(w3.x, x3.x, u); u = fmaf(w3.y, x3.y, u); u = fmaf(w3.z, x3.z, u); u = fmaf(w3.w, x3.w, u);
    return u;
}

// ---------------------------------------------------------------------------
// Kernel A: Z[b,i] = sum_j exp(veff[b,j,:] . u_hat[b,j,i,:])   (no max-sub; |logit|<~6)
// grid 256 = icg*2+bh ; 512 thr = 8 waves x 2 b ; lane = j. W[:,i,:,:] LDS-staged (128 KB).
__global__ __launch_bounds__(512)
void stats_pass(const float* __restrict__ W, const float* __restrict__ x,
                const float* __restrict__ veff, float* __restrict__ Zbuf)
{
    __shared__ float4 Wl[8192];
    const int tid = threadIdx.x;
    const int j   = tid & 63;
    const int wv  = tid >> 6;
    const int bh  = blockIdx.x & 1;
    const int icg = blockIdx.x >> 1;
    const int b0  = bh * 16 + wv * 2;
    const int swz = (j & 7) << 4;
    const int rowb = j << 11;

    // veff rows for (b0,j,:) and (b0+1,j,:) — constant over i, keep in registers
    float vf0[32], vf1[32];
    {
        const float* p0 = veff + (((size_t)b0) << 11) + (j << 5);
        const float* p1 = p0 + 2048;
        #pragma unroll
        for (int mq = 0; mq < 8; ++mq) {
            const float4 a = *(const float4*)(p0 + mq * 4);
            const float4 c = *(const float4*)(p1 + mq * 4);
            vf0[mq*4+0] = a.x; vf0[mq*4+1] = a.y; vf0[mq*4+2] = a.z; vf0[mq*4+3] = a.w;
            vf1[mq*4+0] = c.x; vf1[mq*4+1] = c.y; vf1[mq*4+2] = c.z; vf1[mq*4+3] = c.w;
        }
    }

    for (int ii = 0; ii < 16; ++ii) {
        const int i = icg * 16 + ii;
        __syncthreads();                       // previous iter's LDS reads done
        #pragma unroll
        for (int k = 0; k < 16; ++k) {         // stage W[:, i, :, :] (XOR-swizzled)
            const int f = k * 512 + tid;
            const int jp = f >> 7, rem = f & 127;
            const float4 w4 = *(const float4*)(W + (((size_t)jp << 20) + ((size_t)i << 9) + (rem << 2)));
            *(float4*)((char*)Wl + ((f * 16) ^ ((jp & 7) << 4))) = w4;
        }
        const float* xr0 = x + (((size_t)b0 << 15) + (i << 4));
        const float* xr1 = xr0 + 32768;
        const float4 xa0 = *(const float4*)(xr0 + 0), xa1 = *(const float4*)(xr0 + 4);
        const float4 xa2 = *(const float4*)(xr0 + 8), xa3 = *(const float4*)(xr0 + 12);
        const float4 xb0 = *(const float4*)(xr1 + 0), xb1 = *(const float4*)(xr1 + 4);
        const float4 xb2 = *(const float4*)(xr1 + 8), xb3 = *(const float4*)(xr1 + 12);
        __syncthreads();

        float logit0 = 0.f, logit1 = 0.f;
        const char* wb = (const char*)Wl;
        #pragma unroll
        for (int mq = 0; mq < 8; ++mq) {
            #pragma unroll
            for (int mi = 0; mi < 4; ++mi) {
                const int m  = mq * 4 + mi;
                const int rb = rowb + (m << 6);
                const float4 w0 = *(const float4*)(wb + ((rb +  0) ^ swz));
                const float4 w1 = *(const float4*)(wb + ((rb + 16) ^ swz));
                const float4 w2 = *(const float4*)(wb + ((rb + 32) ^ swz));
                const float4 w3 = *(const float4*)(wb + ((rb + 48) ^ swz));
                const float u0 = dot16(w0,w1,w2,w3, xa0,xa1,xa2,xa3);
                const float u1 = dot16(w0,w1,w2,w3, xb0,xb1,xb2,xb3);
                logit0 = fmaf(u0, vf0[m], logit0);
                logit1 = fmaf(u1, vf1[m], logit1);
            }
        }
        float e0 = __expf(logit0), e1 = __expf(logit1);
        #pragma unroll
        for (int off = 32; off >= 1; off >>= 1) {
            e0 += __shfl_xor(e0, off, 64);
            e1 += __shfl_xor(e1, off, 64);
        }
        if (j == 0) {
            Zbuf[(((size_t)b0) << 11) + i]       = e0;
            Zbuf[(((size_t)(b0+1)) << 11) + i]   = e1;
        }
    }
}

// ---------------------------------------------------------------------------
// Kernel B: s[b,j,:] = sum_i c[b,i,j] u_hat[b,j,i,:] + bias; v = squash(s) (+vold), fused.
// grid 256 = j*4+bq (4 bq-blocks per j dispatch-adjacent -> L3 dedup of W[j]).
// 512 thr = 8 waves: g=wv>>1 (i-group 0..3), h=wv&1 (b-half); wave owns 4 b's, lane=(ip,m).
// Exclusive owner of out[b in its set][j][:] -> no partials, no atomics.
// MODE 0: c = 1/64. MODE 1: c = exp(veff.u_hat)/Z[b,i].
template<int MODE, bool ADDOLD>
__global__ __launch_bounds__(512)
void accum_pass(const float* __restrict__ W, const float* __restrict__ x,
                const float* __restrict__ bias, const float* __restrict__ veff,
                const float* __restrict__ Zbuf, const float* __restrict__ vold,
                float* __restrict__ vout)
{
    __shared__ float4 Wl[4096];               // 64 KB chunk: Wl[ii 32][q 4][m 32] (transposed)
    const int tid = threadIdx.x;
    const int m   = tid & 31;
    const int ip  = (tid >> 5) & 1;
    const int wv  = tid >> 6;                 // 0..7
    const int g   = wv >> 1;                  // i-group
    const int h   = wv & 1;                   // b-half of 8
    const int bq  = blockIdx.x & 3;
    const int j   = blockIdx.x >> 2;
    const int bbase = bq * 8 + h * 4;

    float vf[4] = {0,0,0,0};
    if (MODE) {
        #pragma unroll
        for (int bb = 0; bb < 4; ++bb)
            vf[bb] = veff[(((size_t)(bbase+bb)) << 11) + (j << 5) + m];
    }
    float acc[4] = {0.f, 0.f, 0.f, 0.f};
    const size_t Wbase = ((size_t)j) << 20;

    for (int cch = 0; cch < 64; ++cch) {
        __syncthreads();
        #pragma unroll
        for (int k = 0; k < 8; ++k) {         // stage 32-i chunk, transposed
            const int f = k * 512 + tid;      // 0..4095
            const int fii = f >> 7, r = f & 127, fm = r >> 2, fq = r & 3;
            const float4 w4 = *(const float4*)(W + Wbase + (((size_t)(cch*32 + fii)) << 9) + (r << 2));
            Wl[fii*128 + fq*32 + fm] = w4;
        }
        __syncthreads();
        #pragma unroll
        for (int pp = 0; pp < 4; ++pp) {
            const int ii = (g * 4 + pp) * 2 + ip;   // 0..31
            const int i  = cch * 32 + ii;
            // x rows for the wave's 4 b's (broadcast within half)
            float4 xv0[4], xv1[4], xv2[4], xv3[4];
            #pragma unroll
            for (int bb = 0; bb < 4; ++bb) {
                const float* xr = x + (((size_t)(bbase+bb)) << 15) + (i << 4);
                xv0[bb] = *(const float4*)(xr + 0);
                xv1[bb] = *(const float4*)(xr + 4);
                xv2[bb] = *(const float4*)(xr + 8);
                xv3[bb] = *(const float4*)(xr + 12);
            }
            // W row from LDS (conflict-free: m-contiguous)
            const float4 w0 = Wl[ii*128 + 0*32 + m];
            const float4 w1 = Wl[ii*128 + 1*32 + m];
            const float4 w2 = Wl[ii*128 + 2*32 + m];
            const float4 w3 = Wl[ii*128 + 3*32 + m];
            #pragma unroll
            for (int bb = 0; bb < 4; ++bb) {
                const float u = dot16(w0,w1,w2,w3, xv0[bb],xv1[bb],xv2[bb],xv3[bb]);
                float cw;
                if (MODE) {
                    float t = u * vf[bb];
                    t += __shfl_xor(t, 1, 64); t += __shfl_xor(t, 2, 64);
                    t += __shfl_xor(t, 4, 64); t += __shfl_xor(t, 8, 64);
                    t += __shfl_xor(t, 16, 64);
                    const float zv = Zbuf[(((size_t)(bbase+bb)) << 11) + i];
                    cw = __expf(t) / zv;
                } else {
                    cw = 0.015625f;           // 1/64 exact
                }
                acc[bb] = fmaf(cw, u, acc[bb]);
            }
        }
    }
    // fold i-parity halves
    #pragma unroll
    for (int bb = 0; bb < 4; ++bb) acc[bb] += __shfl_xor(acc[bb], 32, 64);
    // cross-group reduce via LDS (reuse Wl)
    __syncthreads();
    float* sf = (float*)Wl;                   // [g 4][b_local 8][m 32]
    if (ip == 0) {
        #pragma unroll
        for (int bb = 0; bb < 4; ++bb)
            sf[g*256 + (h*4+bb)*32 + m] = acc[bb];
    }
    __syncthreads();
    {
        const int bl = wv;                    // wave -> b_local
        float s = sf[0*256 + bl*32 + m] + sf[1*256 + bl*32 + m]
                + sf[2*256 + bl*32 + m] + sf[3*256 + bl*32 + m];
        s += bias[(j << 5) + m];
        float n2 = s * s;
        n2 += __shfl_xor(n2, 1, 64); n2 += __shfl_xor(n2, 2, 64);
        n2 += __shfl_xor(n2, 4, 64); n2 += __shfl_xor(n2, 8, 64);
        n2 += __shfl_xor(n2, 16, 64);
        float v = s * (n2 / (1.f + n2)) / sqrtf(n2 + FEPS);
        const size_t oidx = (((size_t)(bq*8 + bl)) << 11) + (j << 5) + m;
        if (ADDOLD) v += vold[oidx];
        if (ip == 0) vout[oidx] = v;
    }
}

extern "C" void kernel_launch(void* const* d_in, const int* in_sizes, int n_in,
                              void* d_out, int out_size, void* d_ws, size_t ws_size,
                              hipStream_t stream)
{
    const float* x    = (const float*)d_in[0];
    const float* W    = (const float*)d_in[1];
    const float* bias = (const float*)d_in[2];
    float* out = (float*)d_out;               // running v lives here (disjoint (b,j) per block)
    float* Z   = (float*)d_ws;                // 256 KB

    // it0: c = 1/64  -> out = v0
    accum_pass<0,false><<<256, 512, 0, stream>>>(W, x, bias, nullptr, nullptr, nullptr, out);
    // it1: Z from veff=v0; out = v0 + v1
    stats_pass<<<256, 512, 0, stream>>>(W, x, out, Z);
    accum_pass<1,true ><<<256, 512, 0, stream>>>(W, x, bias, out, Z, out, out);
    // it2: Z from veff=v0+v1; out = v2 (final)
    stats_pass<<<256, 512, 0, stream>>>(W, x, out, Z);
    accum_pass<1,false><<<256, 512, 0, stream>>>(W, x, bias, out, Z, nullptr, out);
}

// Round 5
// 343.912 us; speedup vs baseline: 6.0833x; 5.3462x over previous
//
#include <hip/hip_runtime.h>

// Dims: x[b=32][i=2048][n=16], W[j=64][i=2048][m=32][n=16], bias[j=64][m=32], out v[b=32][j=64][m=32]
// MFMA shape 32x32x16: M=m(32), N=b(32), K=n(16). fp32 -> bf16 hi/lo split, 3 MFMAs/u-tile.
// A frag: lane l holds W[j,i, m=l&31, n=(l>>5)*8+e]  (e=0..7)
// B frag: lane l holds x[b=l&31, i,  n=(l>>5)*8+e]
// C/D:    lane l, reg r = u_hat[b=l&31][m=(r&3)+8*(r>>2)+4*(l>>5)]   (m74/m101-verified)
// ws layout: sbuf[32*64*32] (256 KB, atomic s accum) + Zinv[32*2048] (256 KB). ws>=768KB known-safe.
constexpr float FEPS = 1e-8f;

typedef __attribute__((ext_vector_type(8)))  short bf16x8;
typedef __attribute__((ext_vector_type(16))) float f32x16;

__device__ __forceinline__ short bf16_rne(float f) {
    unsigned u = __float_as_uint(f);
    return (short)((u + 0x7FFFu + ((u >> 16) & 1u)) >> 16);
}
__device__ __forceinline__ float bf16_val(short h) {
    return __uint_as_float(((unsigned)(unsigned short)h) << 16);
}
// 8 floats -> bf16 hi + residual lo fragments
__device__ __forceinline__ void cvt8(float4 a, float4 b, bf16x8& hi, bf16x8& lo) {
    float v[8] = {a.x, a.y, a.z, a.w, b.x, b.y, b.z, b.w};
    #pragma unroll
    for (int e = 0; e < 8; ++e) {
        const short hb = bf16_rne(v[e]);
        hi[e] = hb;
        lo[e] = bf16_rne(v[e] - bf16_val(hb));
    }
}
#define MFMA(A, B, C) __builtin_amdgcn_mfma_f32_32x32x16_bf16((A), (B), (C), 0, 0, 0)

// ---------------------------------------------------------------------------
// stats: Zinv[b,i] = 1 / sum_j exp(veff[b,j,:] . u_hat[b,j,i,:])
// grid 256 = 8-i slab; 512 thr = 8 waves; wave w covers j in {w, w+8, .., w+56}, all 8 i.
// W read exactly once per pass (1 MB/block). Z complete in-block -> no cross-block reduce.
__global__ __launch_bounds__(512, 2)
void stats_pass(const float* __restrict__ W, const float* __restrict__ x,
                const float* __restrict__ veff, float* __restrict__ Zinv)
{
    __shared__ float zred[8][32][9];          // [wave][b][i] (+1 pad)
    const int tid = threadIdx.x;
    const int l = tid & 63, w = tid >> 6;
    const int b = l & 31, h = l >> 5;
    const int i0 = blockIdx.x * 8;

    // hoist the 8 x-fragments (b = lane&31, n-half = lane>>5)
    bf16x8 xh[8], xl[8];
    #pragma unroll
    for (int ii = 0; ii < 8; ++ii) {
        const float* xr = x + (((size_t)b << 15) + ((size_t)(i0 + ii) << 4) + (h << 3));
        cvt8(*(const float4*)xr, *(const float4*)(xr + 4), xh[ii], xl[ii]);
    }
    float zacc[8];
    #pragma unroll
    for (int ii = 0; ii < 8; ++ii) zacc[ii] = 0.f;

    #pragma unroll 1
    for (int jt = 0; jt < 8; ++jt) {
        const int j = w + (jt << 3);
        // veff quads for (b, j): m-offsets {0,8,16,24} + 4h (matches C-row layout)
        const float* vr = veff + ((((size_t)b << 6) | (size_t)j) << 5) + (h << 2);
        const float4 vq0 = *(const float4*)(vr + 0);
        const float4 vq1 = *(const float4*)(vr + 8);
        const float4 vq2 = *(const float4*)(vr + 16);
        const float4 vq3 = *(const float4*)(vr + 24);
        const float* wrow = W + (((size_t)j << 20) + ((size_t)i0 << 9) + (b << 4) + (h << 3));
        #pragma unroll
        for (int ii = 0; ii < 8; ++ii) {
            bf16x8 wh, wl;
            cvt8(*(const float4*)wrow, *(const float4*)(wrow + 4), wh, wl);
            wrow += 512;
            f32x16 u;
            #pragma unroll
            for (int r = 0; r < 16; ++r) u[r] = 0.f;
            u = MFMA(wh, xh[ii], u);
            u = MFMA(wh, xl[ii], u);
            u = MFMA(wl, xh[ii], u);
            float th = 0.f;
            th = fmaf(u[0],  vq0.x, th); th = fmaf(u[1],  vq0.y, th);
            th = fmaf(u[2],  vq0.z, th); th = fmaf(u[3],  vq0.w, th);
            th = fmaf(u[4],  vq1.x, th); th = fmaf(u[5],  vq1.y, th);
            th = fmaf(u[6],  vq1.z, th); th = fmaf(u[7],  vq1.w, th);
            th = fmaf(u[8],  vq2.x, th); th = fmaf(u[9],  vq2.y, th);
            th = fmaf(u[10], vq2.z, th); th = fmaf(u[11], vq2.w, th);
            th = fmaf(u[12], vq3.x, th); th = fmaf(u[13], vq3.y, th);
            th = fmaf(u[14], vq3.z, th); th = fmaf(u[15], vq3.w, th);
            const float t = th + __shfl_xor(th, 32, 64);   // both m-halves
            zacc[ii] += __expf(t);
        }
    }
    if (h == 0) {
        #pragma unroll
        for (int ii = 0; ii < 8; ++ii) zred[w][b][ii] = zacc[ii];
    }
    __syncthreads();
    if (tid < 256) {
        const int bb = tid >> 3, ii = tid & 7;
        float z = 0.f;
        #pragma unroll
        for (int ww = 0; ww < 8; ++ww) z += zred[ww][bb][ii];
        Zinv[((size_t)bb << 11) + i0 + ii] = 1.0f / z;
    }
}

// ---------------------------------------------------------------------------
// accum: s[b,j,:] += sum_i c[b,i,j] * u_hat[b,j,i,:]
// grid 256 = (j<<2)|iq; 512 thr = 8 waves; wave w owns i in [iq*512 + w*64, +64), all 32 b.
// MODE 0: c = 1/64 (MFMA accumulates across i directly). MODE 1: c = exp(veff.u)*Zinv.
// Cross-wave reduce in LDS, then 2 atomicAdds/thread into sbuf (1024/block, 262K total).
template<int MODE>
__global__ __launch_bounds__(512, 2)
void accum_pass(const float* __restrict__ W, const float* __restrict__ x,
                const float* __restrict__ veff, const float* __restrict__ Zinv,
                float* __restrict__ sbuf)
{
    __shared__ float sred[8][32][36];         // [wave][b][m] (+4 pad)
    const int tid = threadIdx.x;
    const int l = tid & 63, w = tid >> 6;
    const int b = l & 31, h = l >> 5;
    const int j  = blockIdx.x >> 2;
    const int iq = blockIdx.x & 3;
    const int ibase = iq * 512 + w * 64;

    float4 vq0, vq1, vq2, vq3;
    if (MODE) {
        const float* vr = veff + ((((size_t)b << 6) | (size_t)j) << 5) + (h << 2);
        vq0 = *(const float4*)(vr + 0);
        vq1 = *(const float4*)(vr + 8);
        vq2 = *(const float4*)(vr + 16);
        vq3 = *(const float4*)(vr + 24);
    }
    f32x16 accs;
    #pragma unroll
    for (int r = 0; r < 16; ++r) accs[r] = 0.f;

    const float* wrow = W + (((size_t)j << 20) + ((size_t)ibase << 9) + (b << 4) + (h << 3));
    #pragma unroll 4
    for (int ii = 0; ii < 64; ++ii) {
        const int i = ibase + ii;
        const float* xr = x + (((size_t)b << 15) + ((size_t)i << 4) + (h << 3));
        bf16x8 xh, xl, wh, wl;
        cvt8(*(const float4*)xr, *(const float4*)(xr + 4), xh, xl);
        cvt8(*(const float4*)wrow, *(const float4*)(wrow + 4), wh, wl);
        wrow += 512;
        if (MODE == 0) {
            accs = MFMA(wh, xh, accs);
            accs = MFMA(wh, xl, accs);
            accs = MFMA(wl, xh, accs);
        } else {
            f32x16 u;
            #pragma unroll
            for (int r = 0; r < 16; ++r) u[r] = 0.f;
            u = MFMA(wh, xh, u);
            u = MFMA(wh, xl, u);
            u = MFMA(wl, xh, u);
            float th = 0.f;
            th = fmaf(u[0],  vq0.x, th); th = fmaf(u[1],  vq0.y, th);
            th = fmaf(u[2],  vq0.z, th); th = fmaf(u[3],  vq0.w, th);
            th = fmaf(u[4],  vq1.x, th); th = fmaf(u[5],  vq1.y, th);
            th = fmaf(u[6],  vq1.z, th); th = fmaf(u[7],  vq1.w, th);
            th = fmaf(u[8],  vq2.x, th); th = fmaf(u[9],  vq2.y, th);
            th = fmaf(u[10], vq2.z, th); th = fmaf(u[11], vq2.w, th);
            th = fmaf(u[12], vq3.x, th); th = fmaf(u[13], vq3.y, th);
            th = fmaf(u[14], vq3.z, th); th = fmaf(u[15], vq3.w, th);
            const float t = th + __shfl_xor(th, 32, 64);
            const float c = __expf(t) * Zinv[((size_t)b << 11) + i];
            #pragma unroll
            for (int r = 0; r < 16; ++r) accs[r] = fmaf(c, u[r], accs[r]);
        }
    }
    const float scale = (MODE == 0) ? 0.015625f : 1.0f;
    #pragma unroll
    for (int q = 0; q < 4; ++q) {
        *(float4*)&sred[w][b][q * 8 + (h << 2)] =
            make_float4(accs[q*4] * scale, accs[q*4+1] * scale,
                        accs[q*4+2] * scale, accs[q*4+3] * scale);
    }
    __syncthreads();
    #pragma unroll
    for (int k = 0; k < 2; ++k) {
        const int idx = tid * 2 + k;
        const int bb = idx >> 5, mm = idx & 31;
        float s = 0.f;
        #pragma unroll
        for (int ww = 0; ww < 8; ++ww) s += sred[ww][bb][mm];
        atomicAdd(sbuf + ((((size_t)bb << 6) | (size_t)j) << 5) + mm, s);
    }
}

// ---------------------------------------------------------------------------
// squash: v = squash(s + bias) (+ vold for the running-veff trick). 8 (b,j) pairs / block.
__global__ __launch_bounds__(256)
void squash_pass(const float* __restrict__ sbuf, const float* __restrict__ bias,
                 float* __restrict__ vout, const float* __restrict__ vold)
{
    const int tid = threadIdx.x;
    const int m = tid & 31, g = tid >> 5;
    const int pair = blockIdx.x * 8 + g;      // b*64 + j
    const int j = pair & 63;
    float s = sbuf[((size_t)pair << 5) + m] + bias[(j << 5) + m];
    float n2 = s * s;
    n2 += __shfl_xor(n2, 1, 64);  n2 += __shfl_xor(n2, 2, 64);
    n2 += __shfl_xor(n2, 4, 64);  n2 += __shfl_xor(n2, 8, 64);
    n2 += __shfl_xor(n2, 16, 64);
    float v = s * (n2 / (1.f + n2)) / sqrtf(n2 + FEPS);
    if (vold) v += vold[((size_t)pair << 5) + m];
    vout[((size_t)pair << 5) + m] = v;
}

extern "C" void kernel_launch(void* const* d_in, const int* in_sizes, int n_in,
                              void* d_out, int out_size, void* d_ws, size_t ws_size,
                              hipStream_t stream)
{
    const float* x    = (const float*)d_in[0];
    const float* W    = (const float*)d_in[1];
    const float* bias = (const float*)d_in[2];
    float* out  = (float*)d_out;              // running veff lives here
    float* sbuf = (float*)d_ws;               // 65536 floats
    float* Zinv = sbuf + 65536;               // 65536 floats
    const size_t sbytes = 65536 * sizeof(float);

    // it0: c = 1/64 exactly
    hipMemsetAsync(sbuf, 0, sbytes, stream);
    accum_pass<0><<<256, 512, 0, stream>>>(W, x, nullptr, nullptr, sbuf);
    squash_pass<<<256, 256, 0, stream>>>(sbuf, bias, out, nullptr);        // out = v0
    // it1
    stats_pass<<<256, 512, 0, stream>>>(W, x, out, Zinv);
    hipMemsetAsync(sbuf, 0, sbytes, stream);
    accum_pass<1><<<256, 512, 0, stream>>>(W, x, out, Zinv, sbuf);
    squash_pass<<<256, 256, 0, stream>>>(sbuf, bias, out, out);            // out = v0 + v1
    // it2
    stats_pass<<<256, 512, 0, stream>>>(W, x, out, Zinv);
    hipMemsetAsync(sbuf, 0, sbytes, stream);
    accum_pass<1><<<256, 512, 0, stream>>>(W, x, out, Zinv, sbuf);
    squash_pass<<<256, 256, 0, stream>>>(sbuf, bias, out, nullptr);        // final v
}